// Round 5
// baseline (2498.105 us; speedup 1.0000x reference)
//
#include <hip/hip_runtime.h>

typedef unsigned short u16;
typedef __attribute__((ext_vector_type(8))) short short8;
typedef __attribute__((ext_vector_type(4))) float f32x4;

__device__ __forceinline__ u16 f2b(float f){
    unsigned u = __builtin_bit_cast(unsigned, f);
    u += 0x7fffu + ((u >> 16) & 1u);   // RNE
    return (u16)(u >> 16);
}
__device__ __forceinline__ float b2f(u16 s){
    unsigned u = ((unsigned)s) << 16;
    return __builtin_bit_cast(float, u);
}
__device__ __forceinline__ float sigm(float x){ return 1.f/(1.f + __expf(-x)); }

// LSTM cell: 5 exp2 + 3 rcp (sigm(i)*tanh(g) and sigm(o)*tanh(c) share one rcp each)
__device__ __forceinline__ float lstm_cell(const f32x4 g, float& cst){
    const float L2E = 1.4426950408889634f;
    float ei = __builtin_amdgcn_exp2f(-L2E * g[0]);
    float ef = __builtin_amdgcn_exp2f(-L2E * g[1]);
    float eg = __builtin_amdgcn_exp2f(-2.f * L2E * g[2]);
    float eo = __builtin_amdgcn_exp2f(-L2E * g[3]);
    float f_s = __builtin_amdgcn_rcpf(1.f + ef);
    float ig  = (1.f - eg) * __builtin_amdgcn_rcpf((1.f + ei) * (1.f + eg));
    float c = fmaf(f_s, cst, ig);
    cst = c;
    float ec = __builtin_amdgcn_exp2f(-2.f * L2E * c);
    return (1.f - ec) * __builtin_amdgcn_rcpf((1.f + eo) * (1.f + ec));
}

// ---------------- fp32 -> bf16 conversion ----------------
__global__ __launch_bounds__(256) void cvt_bf16(const float* __restrict__ s,
                                                u16* __restrict__ d, int n4){
    int i = blockIdx.x*256 + threadIdx.x;
    if (i < n4){
        float4 v = ((const float4*)s)[i];
        ushort4 o;
        o.x = f2b(v.x); o.y = f2b(v.y); o.z = f2b(v.z); o.w = f2b(v.w);
        ((ushort4*)d)[i] = o;
    }
}

// ---- W_ih cvt with row permutation, 4 matrices in one launch ----
// out row (unit*4+gate) = in row (gate*128+unit)
__global__ __launch_bounds__(192) void cvt_wih_perm4(
    const float* __restrict__ s0, const float* __restrict__ s1,
    const float* __restrict__ s2, const float* __restrict__ s3,
    u16* __restrict__ d0, u16* __restrict__ d1){
    const float* s; u16* d;
    switch (blockIdx.y){
        case 0:  s = s0; d = d0;              break;
        case 1:  s = s1; d = d0 + 512*768;    break;
        case 2:  s = s2; d = d1;              break;
        default: s = s3; d = d1 + 512*768;    break;
    }
    int r = blockIdx.x;               // 0..511 input row
    int j = threadIdx.x;              // 0..191 float4 within row
    int g = r >> 7, u = r & 127;
    int ro = u * 4 + g;
    float4 v = ((const float4*)(s + (size_t)r * 768))[j];
    ushort4 o;
    o.x = f2b(v.x); o.y = f2b(v.y); o.z = f2b(v.z); o.w = f2b(v.w);
    ((ushort4*)(d + (size_t)ro * 768))[j] = o;
}

// ---- W_hh cvt + same row permutation (512 x 128), 4 matrices ----
__global__ __launch_bounds__(64) void cvt_whh_perm4(
    const float* __restrict__ s0, const float* __restrict__ s1,
    const float* __restrict__ s2, const float* __restrict__ s3,
    u16* __restrict__ d0, u16* __restrict__ d1,
    u16* __restrict__ d2, u16* __restrict__ d3){
    const float* s; u16* d;
    switch (blockIdx.y){
        case 0:  s = s0; d = d0; break;
        case 1:  s = s1; d = d1; break;
        case 2:  s = s2; d = d2; break;
        default: s = s3; d = d3; break;
    }
    int r = blockIdx.x;               // 0..511 input row (g*128+u)
    int j = threadIdx.x;              // 0..63
    if (j < 32){
        int g = r >> 7, u = r & 127;
        int ro = u * 4 + g;
        float4 v = ((const float4*)(s + (size_t)r * 128))[j];
        ushort4 o;
        o.x = f2b(v.x); o.y = f2b(v.y); o.z = f2b(v.z); o.w = f2b(v.w);
        ((ushort4*)(d + (size_t)ro * 128))[j] = o;
    }
}

// ---------------- embedding-gather + input projection GEMM ----------------
// pre[m, n] = sum_k E[tok[m], k] * Wt[n, k] + bias(n);  M x 1024, K=768
// Wt rows (and hence pre cols) are PERMUTED: within each 512-half, p = unit*4+gate.
__global__ __launch_bounds__(256) void gemm_embed(
    const u16* __restrict__ E, const int* __restrict__ tok,
    const u16* __restrict__ Wt, const float* __restrict__ bf_,
    const float* __restrict__ bb_, u16* __restrict__ pre)
{
    __shared__ __align__(16) u16 Asm[128*32];
    __shared__ __align__(16) u16 Bsm[128*32];
    const int m0 = blockIdx.x * 128, n0 = blockIdx.y * 128;
    const int tid = threadIdx.x;
    const int ar = tid >> 2, ch = (tid & 3) * 8;
    const u16* ap0 = E + (size_t)tok[m0 + ar] * 768 + ch;
    const u16* ap1 = E + (size_t)tok[m0 + 64 + ar] * 768 + ch;
    const u16* bp0 = Wt + (size_t)(n0 + ar) * 768 + ch;
    const u16* bp1 = Wt + (size_t)(n0 + 64 + ar) * 768 + ch;
    const int lane = tid & 63, wave = tid >> 6;
    const int wm = (wave >> 1) * 64, wn = (wave & 1) * 64;
    const int qr = lane >> 4, lr = lane & 15;
    f32x4 acc[4][4] = {};
    for (int k0 = 0; k0 < 768; k0 += 32){
        __syncthreads();
        *(short8*)&Asm[ar*32 + ch]      = *(const short8*)(ap0 + k0);
        *(short8*)&Asm[(64+ar)*32 + ch] = *(const short8*)(ap1 + k0);
        *(short8*)&Bsm[ar*32 + ch]      = *(const short8*)(bp0 + k0);
        *(short8*)&Bsm[(64+ar)*32 + ch] = *(const short8*)(bp1 + k0);
        __syncthreads();
        short8 af[4], bfr[4];
        #pragma unroll
        for (int i = 0; i < 4; ++i){
            af[i]  = *(const short8*)&Asm[(wm + i*16 + lr)*32 + qr*8];
            bfr[i] = *(const short8*)&Bsm[(wn + i*16 + lr)*32 + qr*8];
        }
        #pragma unroll
        for (int i = 0; i < 4; ++i)
            #pragma unroll
            for (int j = 0; j < 4; ++j)
                acc[i][j] = __builtin_amdgcn_mfma_f32_16x16x32_bf16(af[i], bfr[j], acc[i][j], 0, 0, 0);
    }
    #pragma unroll
    for (int j = 0; j < 4; ++j){
        int col = n0 + wn + j*16 + lr;
        int d = col >> 9, p = col & 511;
        int uu = p >> 2, gg = p & 3;
        float bias = (d ? bb_ : bf_)[gg*128 + uu];
        #pragma unroll
        for (int i = 0; i < 4; ++i){
            #pragma unroll
            for (int r = 0; r < 4; ++r){
                int row = m0 + wm + i*16 + qr*4 + r;
                pre[(size_t)row*1024 + col] = f2b(acc[i][j][r] + bias);
            }
        }
    }
}

// ---------------- MFMA LSTM scan v2: 16 chains/WG, 8-step batched loads ----------------
// WG 0,1: word fwd; 2,3: word bwd; 4..35: sent fwd; 36..67: sent bwd.
// G[512 gates, 16 chains] = W_hh (A-frags, registers) x H (B-frags, LDS) + pre.
// A row (within tile) = lane&15 = c; B col = c; C/D row = q*4+r, col = c.
// Gate row p = wv*64 + t*16 + q*4 + r  ->  unit u = wv*16 + t*4 + q, gate r (lane-local cell).
// H LDS layout: idx_u16 = kb*512 + lane*8  (B-frag ds_read_b128 perfectly even, 0 conflicts).
__global__ __launch_bounds__(512, 2) void lstm_scan(
    const u16* __restrict__ preW, const u16* __restrict__ preS,
    const u16* __restrict__ WpWf, const u16* __restrict__ WpWb,
    const u16* __restrict__ WpSf, const u16* __restrict__ WpSb,
    float* __restrict__ fo, float* __restrict__ fs,
    u16* __restrict__ foB, u16* __restrict__ fsB)
{
    const int wg = blockIdx.x;
    const int tid = threadIdx.x;
    const int wv = tid >> 6, l = tid & 63;
    const int c = l & 15, q = l >> 4;

    const u16* pre; const u16* Wp; float* out; u16* outB;
    int T, dir, chain0;
    if (wg < 4){
        dir = (wg >> 1); T = 1024; chain0 = (wg & 1) * 16;
        pre = preW; Wp = dir ? WpWb : WpWf; out = fo; outB = foB;
    } else if (wg < 36){
        dir = 0; T = 64; chain0 = (wg - 4) * 16;
        pre = preS; Wp = WpSf; out = fs; outB = fsB;
    } else {
        dir = 1; T = 64; chain0 = (wg - 36) * 16;
        pre = preS; Wp = WpSb; out = fs; outB = fsB;
    }
    const long rowbase = (long)(chain0 + c) * T;

    // A-fragments of W_hh: row (wv*64 + t*16 + c), k = kb*32 + q*8 + j
    short8 Wf[4][4];
    {
        const u16* wbase = Wp + (size_t)(wv*64 + c) * 128 + q*8;
        #pragma unroll
        for (int t = 0; t < 4; ++t)
            #pragma unroll
            for (int kb = 0; kb < 4; ++kb)
                Wf[t][kb] = *(const short8*)(wbase + (size_t)t*2048 + kb*32);
    }

    __shared__ __align__(16) u16 hA[2048];       // [kb=4][q=4][c=16][j=8]
    __shared__ __align__(16) u16 hB[2048];
    __shared__ __align__(16) float hist[8*16*132];  // [step][chain][132]
    for (int i = tid; i < 2048; i += 512){ hA[i] = 0; hB[i] = 0; }
    __syncthreads();

    float cs0 = 0.f, cs1 = 0.f, cs2 = 0.f, cs3 = 0.f;
    const u16* pgbase = pre + dir*512 + wv*64 + q*4;

#define CELLW(T_, H_, HN)                                                       \
    {   const int u_ = wv*16 + (T_)*4 + q;                                      \
        HN[((u_>>5)<<9) + (((u_>>3)&3)<<7) + (c<<3) + (u_&7)] = f2b(H_);        \
        hrow[u_] = H_; }

#define STEP(S, HC, HN)                                                         \
    {   short8 Bf[4];                                                           \
        _Pragma("unroll")                                                       \
        for (int kb = 0; kb < 4; ++kb)                                          \
            Bf[kb] = *(const short8*)(HC + kb*512 + l*8);                       \
        f32x4 acc[4];                                                           \
        _Pragma("unroll")                                                       \
        for (int t = 0; t < 4; ++t){                                            \
            acc[t][0] = b2f(pb[S][t].x); acc[t][1] = b2f(pb[S][t].y);           \
            acc[t][2] = b2f(pb[S][t].z); acc[t][3] = b2f(pb[S][t].w);           \
        }                                                                       \
        _Pragma("unroll")                                                       \
        for (int kb = 0; kb < 4; ++kb)                                          \
            _Pragma("unroll")                                                   \
            for (int t = 0; t < 4; ++t)                                         \
                acc[t] = __builtin_amdgcn_mfma_f32_16x16x32_bf16(Wf[t][kb], Bf[kb], acc[t], 0, 0, 0); \
        float h0 = lstm_cell(acc[0], cs0);                                      \
        float h1 = lstm_cell(acc[1], cs1);                                      \
        float h2 = lstm_cell(acc[2], cs2);                                      \
        float h3 = lstm_cell(acc[3], cs3);                                      \
        float* hrow = &hist[((S)*16 + c)*132];                                  \
        CELLW(0, h0, HN) CELLW(1, h1, HN) CELLW(2, h2, HN) CELLW(3, h3, HN)     \
        __syncthreads(); }

    for (int it8 = 0; it8 < T; it8 += 8){
        // batch-load 8 steps of pre: ONE vmcnt drain per 8 steps
        ushort4 pb[8][4];
        #pragma unroll
        for (int s = 0; s < 8; ++s){
            long row = rowbase + (dir ? (long)(T-1-(it8+s)) : (long)(it8+s));
            const u16* pp = pgbase + row*1024;
            #pragma unroll
            for (int t = 0; t < 4; ++t) pb[s][t] = *(const ushort4*)(pp + t*16);
        }
        STEP(0, hA, hB) STEP(1, hB, hA) STEP(2, hA, hB) STEP(3, hB, hA)
        STEP(4, hA, hB) STEP(5, hB, hA) STEP(6, hA, hB) STEP(7, hB, hA)
        // coalesced flush of 8 steps x 16 chains x 128 units
        {
            const int cId = tid & 15, oF = (tid >> 4) & 3, sId = tid >> 6;
            const int uF = oF * 32;
            const int itF = it8 + sId;
            long row = (long)(chain0 + cId) * T + (dir ? (long)(T-1-itF) : (long)itF);
            size_t o = (size_t)row * 256 + dir*128 + uF;
            const float* hs = &hist[(sId*16 + cId)*132 + uF];
            #pragma unroll
            for (int v = 0; v < 8; ++v){
                float4 x = *(const float4*)(hs + v*4);
                *(float4*)(out + o + v*4) = x;
                ushort4 y{f2b(x.x), f2b(x.y), f2b(x.z), f2b(x.w)};
                *(ushort4*)(outB + o + v*4) = y;
            }
        }
        __syncthreads();
    }
#undef STEP
#undef CELLW
}

// ---------------- gate GEMM + blend epilogue ----------------
__global__ __launch_bounds__(256) void gemm_gate(
    const u16* __restrict__ foB, const u16* __restrict__ fsB,
    const u16* __restrict__ gW, const float* __restrict__ gb,
    const float* __restrict__ fo, const float* __restrict__ fs,
    float* __restrict__ out)
{
    __shared__ __align__(16) u16 Asm[128*32];
    __shared__ __align__(16) u16 Bsm[128*32];
    const int m0 = blockIdx.x * 128, n0 = blockIdx.y * 128;
    const int tid = threadIdx.x;
    const int ar = tid >> 2, ch = (tid & 3) * 8;
    const u16* af0 = foB + (size_t)(m0 + ar) * 256 + ch;
    const u16* af1 = foB + (size_t)(m0 + 64 + ar) * 256 + ch;
    const u16* as0 = fsB + (size_t)(m0 + ar) * 256 + ch;
    const u16* as1 = fsB + (size_t)(m0 + 64 + ar) * 256 + ch;
    const u16* bp0 = gW + (size_t)(n0 + ar) * 512 + ch;
    const u16* bp1 = gW + (size_t)(n0 + 64 + ar) * 512 + ch;
    const int lane = tid & 63, wave = tid >> 6;
    const int wm = (wave >> 1) * 64, wn = (wave & 1) * 64;
    const int qr = lane >> 4, lr = lane & 15;
    f32x4 acc[4][4] = {};
    for (int k0 = 0; k0 < 512; k0 += 32){
        __syncthreads();
        const u16* s0 = (k0 < 256) ? (af0 + k0) : (as0 + (k0 - 256));
        const u16* s1 = (k0 < 256) ? (af1 + k0) : (as1 + (k0 - 256));
        *(short8*)&Asm[ar*32 + ch]      = *(const short8*)s0;
        *(short8*)&Asm[(64+ar)*32 + ch] = *(const short8*)s1;
        *(short8*)&Bsm[ar*32 + ch]      = *(const short8*)(bp0 + k0);
        *(short8*)&Bsm[(64+ar)*32 + ch] = *(const short8*)(bp1 + k0);
        __syncthreads();
        short8 af[4], bfr[4];
        #pragma unroll
        for (int i = 0; i < 4; ++i){
            af[i]  = *(const short8*)&Asm[(wm + i*16 + lr)*32 + qr*8];
            bfr[i] = *(const short8*)&Bsm[(wn + i*16 + lr)*32 + qr*8];
        }
        #pragma unroll
        for (int i = 0; i < 4; ++i)
            #pragma unroll
            for (int j = 0; j < 4; ++j)
                acc[i][j] = __builtin_amdgcn_mfma_f32_16x16x32_bf16(af[i], bfr[j], acc[i][j], 0, 0, 0);
    }
    #pragma unroll
    for (int j = 0; j < 4; ++j){
        int col = n0 + wn + j*16 + lr;
        float bias = gb[col];
        #pragma unroll
        for (int i = 0; i < 4; ++i){
            #pragma unroll
            for (int r = 0; r < 4; ++r){
                int row = m0 + wm + i*16 + qr*4 + r;
                size_t o = (size_t)row*256 + col;
                float gamma = sigm(acc[i][j][r] + bias);
                out[o] = gamma * fo[o] + (1.f - gamma) * fs[o];
            }
        }
    }
}

extern "C" void kernel_launch(void* const* d_in, const int* in_sizes, int n_in,
                              void* d_out, int out_size, void* d_ws, size_t ws_size,
                              hipStream_t stream)
{
    (void)in_sizes; (void)n_in; (void)out_size; (void)ws_size;
    const int*   wordTok = (const int*)d_in[0];
    const int*   sentTok = (const int*)d_in[1];
    const float* E       = (const float*)d_in[3];
    const float* WihWf   = (const float*)d_in[4];
    const float* WhhWf   = (const float*)d_in[5];
    const float* bWf     = (const float*)d_in[6];
    const float* WihWb   = (const float*)d_in[7];
    const float* WhhWb   = (const float*)d_in[8];
    const float* bWb     = (const float*)d_in[9];
    const float* WihSf   = (const float*)d_in[10];
    const float* WhhSf   = (const float*)d_in[11];
    const float* bSf     = (const float*)d_in[12];
    const float* WihSb   = (const float*)d_in[13];
    const float* WhhSb   = (const float*)d_in[14];
    const float* bSb     = (const float*)d_in[15];
    const float* gateW   = (const float*)d_in[16];
    const float* gateB   = (const float*)d_in[17];
    float* out = (float*)d_out;

    char* w = (char*)d_ws;
    u16* Eb   = (u16*)w;  w += (size_t)30522*768*2;
    u16* Ww   = (u16*)w;  w += (size_t)1024*768*2;
    u16* Ws_  = (u16*)w;  w += (size_t)1024*768*2;
    u16* gWb  = (u16*)w;  w += (size_t)256*512*2;
    u16* WpWf = (u16*)w;  w += (size_t)512*128*2;
    u16* WpWb = (u16*)w;  w += (size_t)512*128*2;
    u16* WpSf = (u16*)w;  w += (size_t)512*128*2;
    u16* WpSb = (u16*)w;  w += (size_t)512*128*2;
    u16* preW = (u16*)w;  w += (size_t)32768*1024*2;
    u16* preS = (u16*)w;  w += (size_t)32768*1024*2;
    float* fo = (float*)w; w += (size_t)32768*256*4;
    float* fs = (float*)w; w += (size_t)32768*256*4;
    u16* foB  = (u16*)w;  w += (size_t)32768*256*2;
    u16* fsB  = (u16*)w;  w += (size_t)32768*256*2;

    const int nE4 = 30522*768/4;
    cvt_bf16<<<(nE4+255)/256, 256, 0, stream>>>(E, Eb, nE4);
    cvt_wih_perm4<<<dim3(512,4), 192, 0, stream>>>(WihWf, WihWb, WihSf, WihSb, Ww, Ws_);
    cvt_whh_perm4<<<dim3(512,4), 64, 0, stream>>>(WhhWf, WhhWb, WhhSf, WhhSb,
                                                  WpWf, WpWb, WpSf, WpSb);
    const int nG4 = 256*512/4;
    cvt_bf16<<<(nG4+255)/256, 256, 0, stream>>>(gateW, gWb, nG4);

    gemm_embed<<<dim3(256,8), 256, 0, stream>>>(Eb, wordTok, Ww, bWf, bWb, preW);
    gemm_embed<<<dim3(256,8), 256, 0, stream>>>(Eb, sentTok, Ws_, bSf, bSb, preS);
    lstm_scan<<<68, 512, 0, stream>>>(preW, preS, WpWf, WpWb, WpSf, WpSb,
                                      fo, fs, foB, fsB);
    gemm_gate<<<dim3(256,2), 256, 0, stream>>>(foB, fsB, gWb, gateB, fo, fs, out);
}